// Round 6
// baseline (152.724 us; speedup 1.0000x reference)
//
#include <hip/hip_runtime.h>

// ProtoNet loss pipeline on MI355X (gfx950) — round 6.
// C=256 classes, S=5 support, Q=64 queries, D_IN=1024, Z=128.
//
// Round-6: k_gemm_z redesigned around the two diagnosed failures:
//  (r2/r3) 1 wave/SIMD grid -> compiler load-sinking fatal;
//  (r4/r5) 260 big blocks @ 1 block/CU -> grid quantization (4 CUs run 2
//          sequential blocks = 2x wall) + per-barrier vmcnt drain exposed.
// New: 1040 blocks x 256 thr (4160 wave-tasks ~ 4 waves/SIMD, self-balancing),
// block = one 16-row group, K split across the 4 waves (256 each), B frags in
// registers straight from L2-hot Wt, NO barriers in the K-loop (vmcnt drains
// never gate; TLP hides latency even if ILP is compiler-killed). Single LDS
// cross-wave reduction at the end (34 KB, 2 barriers).
// k_prep, k_d2red unchanged (controls).

typedef __attribute__((ext_vector_type(8))) short s8v;
typedef __attribute__((ext_vector_type(4))) float f32x4;

__device__ __forceinline__ short f2bf(float f) {
  union { float f; unsigned u; } v; v.f = f;
  unsigned r = (v.u + 0x7fffu + ((v.u >> 16) & 1u)) >> 16;   // RNE
  return (short)r;
}

// blocks 0..255: xbar[c,:] = mean_s xs[c,s,:]; block 0 also zeroes out[0..1].
// blocks 256..271: Wt[n][k] = bf16(W[k][n]) via LDS transpose (64 k-rows each).
__global__ __launch_bounds__(256) void k_prep(
    const float* __restrict__ xs, const float* __restrict__ W,
    float* __restrict__ xbar, unsigned short* __restrict__ Wt,
    float* __restrict__ out) {
  __shared__ unsigned short T[128 * 68];
  const int tid = threadIdx.x;
  if (blockIdx.x < 256) {
    const int c = blockIdx.x;
    if (c == 0 && tid < 2) out[tid] = 0.0f;
    const float* b = xs + (size_t)c * 5120;
    for (int e = tid; e < 1024; e += 256) {
      float s = b[e] + b[1024 + e] + b[2048 + e] + b[3072 + e] + b[4096 + e];
      xbar[(size_t)c * 1024 + e] = s * 0.2f;
    }
  } else {
    const int kb = (blockIdx.x - 256) * 64;
#pragma unroll
    for (int s = 0; s < 8; ++s) {          // 2048 float4 = 64 k x 32 n4
      int idx = tid + s * 256;
      int kr = idx >> 5, n4 = idx & 31;
      float4 v = *(const float4*)(W + (size_t)(kb + kr) * 128 + n4 * 4);
      T[(n4 * 4 + 0) * 68 + kr] = (unsigned short)f2bf(v.x);
      T[(n4 * 4 + 1) * 68 + kr] = (unsigned short)f2bf(v.y);
      T[(n4 * 4 + 2) * 68 + kr] = (unsigned short)f2bf(v.z);
      T[(n4 * 4 + 3) * 68 + kr] = (unsigned short)f2bf(v.w);
    }
    __syncthreads();
#pragma unroll
    for (int s = 0; s < 8; ++s) {          // 2048 ushort4 = 128 n x 16 k4
      int idx = tid + s * 256;
      int n = idx >> 4, k4 = idx & 15;
      ushort4 o;
      o.x = T[n * 68 + k4 * 4 + 0];
      o.y = T[n * 68 + k4 * 4 + 1];
      o.z = T[n * 68 + k4 * 4 + 2];
      o.w = T[n * 68 + k4 * 4 + 3];
      *(ushort4*)(Wt + (size_t)n * 1024 + kb + k4 * 4) = o;
    }
  }
}

// ---------------- z = [xbar ; xq] @ W,  M=16640 N=128 K=1024 ----------------
// 1040 blocks x 256 threads. Block = rows rb..rb+15. Wave w accumulates the
// K-slice [w*256, w*256+256) into a 16x128 fp32 tile; LDS combine at the end.
__global__ __launch_bounds__(256) void k_gemm_z(
    const float* __restrict__ xbar, const float* __restrict__ xq,
    const unsigned short* __restrict__ Wt,
    unsigned short* __restrict__ zb, float* __restrict__ n2) {
  __shared__ float R[4][16][132];          // 33.8 KB; stride 132 (bank-benign)
  const int tid = threadIdx.x;
  const int w = tid >> 6, l = tid & 63, ln = l & 15, qd = l >> 4;
  const int rb = blockIdx.x * 16;
  const float* abase = (rb < 256) ? (xbar + (size_t)rb * 1024)
                                  : (xq + (size_t)(rb - 256) * 1024);
  // lane's A stream: row ln, k = w*256 + kt*32 + qd*8 (+0/+4)
  const float* arow = abase + (size_t)ln * 1024 + w * 256 + qd * 8;
  // lane's B stream: col t*16+ln, same k slice (Wt row-major [n][k])
  const unsigned short* bbase = Wt + (size_t)ln * 1024 + w * 256 + qd * 8;

  f32x4 acc[8] = {};
  float4 a0c = *(const float4*)(arow + 0);
  float4 a1c = *(const float4*)(arow + 4);
  s8v bc[8];
#pragma unroll
  for (int t = 0; t < 8; ++t)
    bc[t] = *(const s8v*)(bbase + (size_t)t * 16384);

#pragma unroll
  for (int kt = 0; kt < 8; ++kt) {
    float4 a0n, a1n;
    s8v bn[8];
    if (kt < 7) {
      a0n = *(const float4*)(arow + (kt + 1) * 32);
      a1n = *(const float4*)(arow + (kt + 1) * 32 + 4);
#pragma unroll
      for (int t = 0; t < 8; ++t)
        bn[t] = *(const s8v*)(bbase + (size_t)t * 16384 + (kt + 1) * 32);
    }
    s8v af = { f2bf(a0c.x), f2bf(a0c.y), f2bf(a0c.z), f2bf(a0c.w),
               f2bf(a1c.x), f2bf(a1c.y), f2bf(a1c.z), f2bf(a1c.w) };
#pragma unroll
    for (int t = 0; t < 8; ++t)
      acc[t] = __builtin_amdgcn_mfma_f32_16x16x32_bf16(af, bc[t], acc[t], 0, 0, 0);
    if (kt < 7) {
      a0c = a0n; a1c = a1n;
#pragma unroll
      for (int t = 0; t < 8; ++t) bc[t] = bn[t];
    }
  }

  // cross-wave K-combine: all waves deposit, then 256 threads vector-combine.
#pragma unroll
  for (int p = 0; p < 4; ++p)
#pragma unroll
    for (int t = 0; t < 8; ++t)
      R[w][qd * 4 + p][t * 16 + ln] = acc[t][p];   // row=qd*4+p, col=t*16+ln
  __syncthreads();
  {
    const int r = tid >> 4, cc = (tid & 15) * 8;
    float v[8];
#pragma unroll
    for (int e = 0; e < 8; ++e)
      v[e] = R[0][r][cc + e] + R[1][r][cc + e] + R[2][r][cc + e] + R[3][r][cc + e];
    s8v o = { f2bf(v[0]), f2bf(v[1]), f2bf(v[2]), f2bf(v[3]),
              f2bf(v[4]), f2bf(v[5]), f2bf(v[6]), f2bf(v[7]) };
    const int grow = rb + r;
    *(s8v*)&zb[(size_t)grow * 128 + cc] = o;
    float sp = 0.0f;
#pragma unroll
    for (int e = 0; e < 8; ++e) sp += v[e] * v[e];
    sp += __shfl_xor(sp, 1);    // 16 threads per row are 16 contiguous lanes
    sp += __shfl_xor(sp, 2);
    sp += __shfl_xor(sp, 4);
    sp += __shfl_xor(sp, 8);
    if ((tid & 15) == 0) n2[grow] = sp;
  }
}

// --------- fused d2 GEMM (64 queries x 256 protos) + per-class reduce ---------
__global__ __launch_bounds__(256, 1) void k_d2red(
    const unsigned short* __restrict__ zb, const float* __restrict__ n2,
    float* __restrict__ out) {
  __shared__ float Dt[256 * 65];          // Dt[j][q], stride 65 (bank-free)
  __shared__ float rv[256];
  __shared__ int   ri[256];
  __shared__ float rss[256];
  __shared__ float invn[64];
  __shared__ float sred[4];
  __shared__ float s_tc, s_aq2, s_corr;
  const int tid = threadIdx.x;
  const int c = blockIdx.x;
  const int w = tid >> 6, lane = tid & 63, ln = lane & 15, qd = lane >> 4;

  // d2 tile via MFMA: wave w handles query rows c*64 + w*16 .. +15
  f32x4 acc[16] = {};
  const unsigned short* Az = zb + (size_t)(256 + c * 64 + w * 16 + ln) * 128;
#pragma unroll
  for (int kt = 0; kt < 4; ++kt) {
    s8v af = *(const s8v*)(Az + kt * 32 + qd * 8);
#pragma unroll
    for (int t = 0; t < 16; ++t) {
      s8v bf = *(const s8v*)(zb + (size_t)(t * 16 + ln) * 128 + kt * 32 + qd * 8);
      acc[t] = __builtin_amdgcn_mfma_f32_16x16x32_bf16(af, bf, acc[t], 0, 0, 0);
    }
  }
#pragma unroll
  for (int p = 0; p < 4; ++p) {
    int qloc = w * 16 + qd * 4 + p;
    float qn = n2[256 + c * 64 + qloc];
#pragma unroll
    for (int t = 0; t < 16; ++t) {
      int j = t * 16 + ln;
      Dt[j * 65 + qloc] = qn + n2[j] - 2.0f * acc[t][p];
    }
  }
  __syncthreads();

  // per-row (query) stats: thread tid handles row q=tid&63, j-quarter (tid>>6)
  {
    const int q = tid & 63, jb = (tid >> 6) * 64;
    float mn = 3.4e38f; int mi = 0; float ss = 0.0f;
    for (int jj = 0; jj < 64; ++jj) {
      int j = jb + jj;
      float f = Dt[j * 65 + q];
      ss += f * f;
      if (f < mn) { mn = f; mi = j; }
    }
    rv[tid] = mn; ri[tid] = mi; rss[tid] = ss;
  }
  __syncthreads();
  if (tid < 64) {   // combine quarters; ascending h + strict < => first-occurrence
    float bm = rv[tid]; int bi = ri[tid]; float ss = rss[tid];
    for (int hh = 1; hh < 4; ++hh) {
      float v = rv[hh * 64 + tid];
      ss += rss[hh * 64 + tid];
      if (v < bm) { bm = v; bi = ri[hh * 64 + tid]; }
    }
    float col = Dt[c * 65 + tid];
    float loo2 = fmaxf(ss - col * col, 0.0f);
    float nrm = fmaxf(sqrtf(loo2), 1e-8f);
    float inv = 1.0f / nrm;
    invn[tid] = inv;
    float aq2 = loo2 * inv * inv;          // ||a_q||^2
    float corr = (bi == c) ? 1.0f : 0.0f;
    for (int m = 1; m < 64; m <<= 1) {
      aq2 += __shfl_xor(aq2, m);
      corr += __shfl_xor(corr, m);
    }
    if (tid == 0) { s_aq2 = aq2; s_corr = corr; }
  }
  __syncthreads();
  // t[j] = sum_q D[q][j] * invn[q]; thread tid = j
  float t = 0.0f;
  for (int qq = 0; qq < 64; ++qq) t += Dt[tid * 65 + qq] * invn[qq];
  if (tid == c) s_tc = t;
  float t2 = t * t;
  for (int m = 1; m < 64; m <<= 1) t2 += __shfl_xor(t2, m);
  if ((tid & 63) == 0) sred[tid >> 6] = t2;
  __syncthreads();
  if (tid == 0) {
    float S2 = sred[0] + sred[1] + sred[2] + sred[3];
    float bs = 0.5f * (S2 - s_tc * s_tc - s_aq2);   // sum_{q<k} sim
    atomicAdd(&out[0], bs * (1.0f / 516096.0f));    // / (C * Q*(Q-1)/2)
    atomicAdd(&out[1], s_corr * (1.0f / 16384.0f)); // / (C*Q)
  }
}

extern "C" void kernel_launch(void* const* d_in, const int* in_sizes, int n_in,
                              void* d_out, int out_size, void* d_ws, size_t ws_size,
                              hipStream_t stream) {
  const float* xs = (const float*)d_in[0];   // 256*5*1024
  const float* xq = (const float*)d_in[1];   // 256*64*1024
  const float* W  = (const float*)d_in[2];   // 1024*128
  float* out = (float*)d_out;

  float* ws = (float*)d_ws;
  float* xbar = ws;                                    // 262144 fp32 (1 MB)
  unsigned short* Wt = (unsigned short*)(xbar + 262144);          // 128K bf16
  unsigned short* zb = Wt + 131072;                               // 16640*128 bf16
  float* n2 = (float*)(zb + (size_t)16640 * 128);                 // 16640 fp32

  k_prep<<<dim3(272), dim3(256), 0, stream>>>(xs, W, xbar, Wt, out);
  k_gemm_z<<<dim3(1040), dim3(256), 0, stream>>>(xbar, xq, Wt, zb, n2);
  k_d2red<<<dim3(256), dim3(256), 0, stream>>>(zb, n2, out);
}